// Round 9
// baseline (181.894 us; speedup 1.0000x reference)
//
#include <hip/hip_runtime.h>

#define N_   8192
#define FIN  256
#define FOUT 128
#define NW   (N_ / 32)   // bitmask words per row = 256

typedef _Float16 f16x8 __attribute__((ext_vector_type(8)));
typedef _Float16 f16x4 __attribute__((ext_vector_type(4)));
typedef float    f32x4 __attribute__((ext_vector_type(4)));
typedef unsigned int uint;

// ---------------- Kernel 0: pack adj (int32 0/1) -> bitmask (proven streamer) -
__global__ __launch_bounds__(256) void k_pack(
    const int* __restrict__ adj, uint* __restrict__ bm)
{
    const int wid = (blockIdx.x * 256 + threadIdx.x) >> 6;   // row 0..8191
    const int l   = threadIdx.x & 63;
    const int4* __restrict__ arow = (const int4*)(adj + (size_t)wid * N_);
    uint* __restrict__ brow = bm + (size_t)wid * NW;

    #pragma unroll 2
    for (int jb = 0; jb < 32; ++jb) {
        int4 av = arow[jb * 64 + l];
        uint nib = (uint)(av.x != 0) | ((uint)(av.y != 0) << 1)
                 | ((uint)(av.z != 0) << 2) | ((uint)(av.w != 0) << 3);
        uint v = nib | (__shfl_xor(nib, 1, 64) << 4);
        v = v | (__shfl_xor(v, 2, 64) << 8);
        v = v | (__shfl_xor(v, 4, 64) << 16);
        if ((l & 7) == 0)
            brow[jb * 8 + (l >> 3)] = v;
    }
}

// ---------------- Kernel 1: Wh = h @ W, s1 = Wh@a1, s2 = Wh@a2 ----------------
// s1/s2 pre-scaled by 1/ln2 for exp2 in k_attn.
__global__ __launch_bounds__(256) void k_wh(
    const float* __restrict__ h, const float* __restrict__ W,
    const float* __restrict__ a, float* __restrict__ Wh,
    float* __restrict__ s1, float* __restrict__ s2)
{
    __shared__ float hrow[2][FIN];
    __shared__ float rbuf[2][2][2];
    const int t   = threadIdx.x;
    const int rh  = t >> 7;
    const int c   = t & 127;
    const int row = (blockIdx.x << 1) + rh;

    hrow[rh][c]       = h[(size_t)row * FIN + c];
    hrow[rh][c + 128] = h[(size_t)row * FIN + c + 128];
    __syncthreads();

    float acc = 0.f;
    #pragma unroll 8
    for (int k = 0; k < FIN; ++k)
        acc = fmaf(hrow[rh][k], W[k * FOUT + c], acc);

    Wh[(size_t)row * FOUT + c] = acc;

    float p1 = acc * a[c];
    float p2 = acc * a[FOUT + c];
    #pragma unroll
    for (int off = 32; off; off >>= 1) {
        p1 += __shfl_down(p1, off, 64);
        p2 += __shfl_down(p2, off, 64);
    }
    if ((t & 63) == 0) { rbuf[rh][c >> 6][0] = p1; rbuf[rh][c >> 6][1] = p2; }
    __syncthreads();
    if (c == 0) {
        const float k2 = 1.44269504088896f;  // 1/ln2
        s1[row] = (rbuf[rh][0][0] + rbuf[rh][1][0]) * k2;
        s2[row] = (rbuf[rh][0][1] + rbuf[rh][1][1]) * k2;
    }
}

// ------- Kernel 2: transpose+convert Wh -> j-tiled fp16 WhTt[j/32][128][32] ---
__global__ __launch_bounds__(256) void k_tr(
    const float* __restrict__ Wh, _Float16* __restrict__ WhTt)
{
    __shared__ float tile[64][129];
    const int t = threadIdx.x;
    const int rbase = blockIdx.x * 64;      // j-range [rbase, rbase+64)

    #pragma unroll
    for (int q = 0; q < 8; ++q) {
        int i4 = q * 256 + t;
        int r  = i4 >> 5;
        int c4 = (i4 & 31) * 4;
        *(float4*)&tile[r][c4] = *(const float4*)&Wh[(size_t)(rbase + r) * FOUT + c4];
    }
    __syncthreads();

    const int c = t >> 1, half = t & 1;     // col 0..127, j-half 0..1
    _Float16 buf[32];
    #pragma unroll
    for (int r = 0; r < 32; ++r) buf[r] = (_Float16)tile[32 * half + r][c];
    _Float16* dst = WhTt + (size_t)(rbase / 32 + half) * 4096 + c * 32;
    #pragma unroll
    for (int q = 0; q < 4; ++q)
        *(f16x8*)(dst + 8 * q) = *(f16x8*)&buf[8 * q];
}

// ---------------- Kernel 3: barrier-free, L2-resident attention numerator -----
// Grid: 1024 blocks = 128 row-blocks(64 rows) x 8 j-splits (1024 j each);
// sp = blockIdx&7 pins each sp's 1MB mask slice + 256KB B slice to one XCD L2.
// Block: 256 thr = 4 waves; wave = 16 rows x 1024 j = 32 tiles of 32 j.
// NO LDS/barriers: lane computes P[row=l&15][j=8*(l>>4)+e] == MFMA A-fragment.
// Mask prefetched distance-4 (named slots, reload-after-consume); s2 double-
// slot distance-1; B issued ~230 VALU-cycles before its MFMA consume.
__global__ __launch_bounds__(256) void k_attn(
    const uint* __restrict__ bm, const _Float16* __restrict__ WhTt,
    const float* __restrict__ s1g, const float* __restrict__ s2g,
    _Float16* __restrict__ num_g, float* __restrict__ den_g)
{
    const int t = threadIdx.x;
    const int w = t >> 6, l = t & 63;
    const int ln15 = l & 15, lq = l >> 4;
    const int shiftM = lq << 3;

    const int sp    = blockIdx.x & 7;
    const int rblk  = blockIdx.x >> 3;        // 0..127
    const int rbase = rblk * 64 + w * 16;
    const int jbase = sp * 1024;

    const int   row = rbase + ln15;
    const float s1r = s1g[row];
    const uint*     __restrict__ mrow = bm + (size_t)row * NW + sp * 32;
    const float*    __restrict__ s2p  = s2g + jbase + 8 * lq;
    const _Float16* __restrict__ bp   =
        WhTt + (size_t)(sp * 32) * 4096 + ln15 * 32 + 8 * lq;

    f32x4 acc[8];
    #pragma unroll
    for (int g = 0; g < 8; ++g) acc[g] = (f32x4){0.f, 0.f, 0.f, 0.f};
    float denp = 0.f;

    // one tile: load B(t) + s2(t+1) + reload mask slot with t+4; P from regs.
    auto sub = [&](int tt, uint& mk, const float4& sa0, const float4& sa1,
                   float4& sb0, float4& sb1) {
        const _Float16* bt = bp + (size_t)tt * 4096;
        f16x8 B0 = *(const f16x8*)(bt);
        f16x8 B1 = *(const f16x8*)(bt + 512);
        f16x8 B2 = *(const f16x8*)(bt + 1024);
        f16x8 B3 = *(const f16x8*)(bt + 1536);
        f16x8 B4 = *(const f16x8*)(bt + 2048);
        f16x8 B5 = *(const f16x8*)(bt + 2560);
        f16x8 B6 = *(const f16x8*)(bt + 3072);
        f16x8 B7 = *(const f16x8*)(bt + 3584);

        const int tn = (tt + 1 < 32) ? tt + 1 : 31;
        sb0 = *(const float4*)(s2p + tn * 32);
        sb1 = *(const float4*)(s2p + tn * 32 + 4);

        const float bias = -5.77078016f;   // -4/ln2
        const uint byte = (mk >> shiftM) & 255u;
        float m, e;
        f16x8 pv;
        m = s1r + sa0.x; e = fmaxf(m, 0.2f * m); pv[0] = (_Float16)((byte & 1u)   ? __builtin_amdgcn_exp2f(e + bias) : 0.f);
        m = s1r + sa0.y; e = fmaxf(m, 0.2f * m); pv[1] = (_Float16)((byte & 2u)   ? __builtin_amdgcn_exp2f(e + bias) : 0.f);
        m = s1r + sa0.z; e = fmaxf(m, 0.2f * m); pv[2] = (_Float16)((byte & 4u)   ? __builtin_amdgcn_exp2f(e + bias) : 0.f);
        m = s1r + sa0.w; e = fmaxf(m, 0.2f * m); pv[3] = (_Float16)((byte & 8u)   ? __builtin_amdgcn_exp2f(e + bias) : 0.f);
        m = s1r + sa1.x; e = fmaxf(m, 0.2f * m); pv[4] = (_Float16)((byte & 16u)  ? __builtin_amdgcn_exp2f(e + bias) : 0.f);
        m = s1r + sa1.y; e = fmaxf(m, 0.2f * m); pv[5] = (_Float16)((byte & 32u)  ? __builtin_amdgcn_exp2f(e + bias) : 0.f);
        m = s1r + sa1.z; e = fmaxf(m, 0.2f * m); pv[6] = (_Float16)((byte & 64u)  ? __builtin_amdgcn_exp2f(e + bias) : 0.f);
        m = s1r + sa1.w; e = fmaxf(m, 0.2f * m); pv[7] = (_Float16)((byte & 128u) ? __builtin_amdgcn_exp2f(e + bias) : 0.f);
        denp += (float)pv[0] + (float)pv[1] + (float)pv[2] + (float)pv[3]
              + (float)pv[4] + (float)pv[5] + (float)pv[6] + (float)pv[7];

        const int ta = (tt + 4 < 32) ? tt + 4 : 31;
        mk = mrow[ta];                      // distance-4 reload, same named slot

        __builtin_amdgcn_s_setprio(1);
        acc[0] = __builtin_amdgcn_mfma_f32_16x16x32_f16(pv, B0, acc[0], 0, 0, 0);
        acc[1] = __builtin_amdgcn_mfma_f32_16x16x32_f16(pv, B1, acc[1], 0, 0, 0);
        acc[2] = __builtin_amdgcn_mfma_f32_16x16x32_f16(pv, B2, acc[2], 0, 0, 0);
        acc[3] = __builtin_amdgcn_mfma_f32_16x16x32_f16(pv, B3, acc[3], 0, 0, 0);
        acc[4] = __builtin_amdgcn_mfma_f32_16x16x32_f16(pv, B4, acc[4], 0, 0, 0);
        acc[5] = __builtin_amdgcn_mfma_f32_16x16x32_f16(pv, B5, acc[5], 0, 0, 0);
        acc[6] = __builtin_amdgcn_mfma_f32_16x16x32_f16(pv, B6, acc[6], 0, 0, 0);
        acc[7] = __builtin_amdgcn_mfma_f32_16x16x32_f16(pv, B7, acc[7], 0, 0, 0);
        __builtin_amdgcn_s_setprio(0);
    };

    // prologue: 4 mask slots (tiles 0-3), s2 slot A (tile 0)
    uint mk0 = mrow[0], mk1 = mrow[1], mk2 = mrow[2], mk3 = mrow[3];
    float4 sA0 = *(const float4*)(s2p);
    float4 sA1 = *(const float4*)(s2p + 4);
    float4 sB0, sB1;

    for (int tt = 0; tt < 32; tt += 4) {
        sub(tt,     mk0, sA0, sA1, sB0, sB1);
        sub(tt + 1, mk1, sB0, sB1, sA0, sA1);
        sub(tt + 2, mk2, sA0, sA1, sB0, sB1);
        sub(tt + 3, mk3, sB0, sB1, sA0, sA1);
    }

    // den: combine the 4 q-lanes of each row
    denp += __shfl_xor(denp, 16, 64);
    denp += __shfl_xor(denp, 32, 64);
    if (l < 16)
        den_g[(size_t)sp * N_ + row] = denp;

    // num partials (f16): C row = 4*lq+e, col = 16*g+ln15
    #pragma unroll
    for (int g = 0; g < 8; ++g) {
        #pragma unroll
        for (int e = 0; e < 4; ++e)
            num_g[((size_t)sp * N_ + rbase + 4 * lq + e) * FOUT + 16 * g + ln15]
                = (_Float16)acc[g][e];
    }
}

// ---------------- Kernel 4: combine 8 j-splits and normalize ------------------
__global__ __launch_bounds__(256) void k_norm(
    const _Float16* __restrict__ num_g, const float* __restrict__ den_g,
    float* __restrict__ out)
{
    const int idx4 = blockIdx.x * 256 + threadIdx.x;
    const int i  = idx4 >> 5;
    const int c4 = (idx4 & 31) * 4;

    float4 s = {0.f, 0.f, 0.f, 0.f};
    float  d = 0.f;
    #pragma unroll
    for (int sp = 0; sp < 8; ++sp) {
        f16x4 v = *(const f16x4*)(num_g + ((size_t)sp * N_ + i) * FOUT + c4);
        s.x += (float)v[0]; s.y += (float)v[1];
        s.z += (float)v[2]; s.w += (float)v[3];
        d += den_g[(size_t)sp * N_ + i];
    }
    const float inv = 1.f / d;
    float4 o = {s.x * inv, s.y * inv, s.z * inv, s.w * inv};
    *(float4*)&out[(size_t)i * FOUT + c4] = o;
}

extern "C" void kernel_launch(void* const* d_in, const int* in_sizes, int n_in,
                              void* d_out, int out_size, void* d_ws, size_t ws_size,
                              hipStream_t stream) {
    const float* h   = (const float*)d_in[0];
    const int*   adj = (const int*)d_in[1];
    const float* W   = (const float*)d_in[2];
    const float* a   = (const float*)d_in[3];
    float* out = (float*)d_out;

    char* ws = (char*)d_ws;
    float*    Wh   = (float*)ws;                           // 0..4 MB
    _Float16* WhTt = (_Float16*)(ws + (4u << 20));         // 4..6 MB
    float*    s1   = (float*)(ws + (6u << 20));            // 32 KB
    float*    s2   = (float*)(ws + (6u << 20) + 32768);    // 32 KB
    _Float16* num  = (_Float16*)(ws + (7u << 20));         // 7..23 MB (f16)
    float*    den  = (float*)(ws + (23u << 20));           // 256 KB
    uint*     bmk  = (uint*)(ws + (24u << 20));            // 24..32 MB

    k_pack<<<2048,   256, 0, stream>>>(adj, bmk);
    k_wh  <<<N_ / 2, 256, 0, stream>>>(h, W, a, Wh, s1, s2);
    k_tr  <<<N_ / 64, 256, 0, stream>>>(Wh, WhTt);
    k_attn<<<1024,  256, 0, stream>>>(bmk, WhTt, s1, s2, num, den);
    k_norm<<<1024,  256, 0, stream>>>(num, den, out);
}

// Round 10
// 133.851 us; speedup vs baseline: 1.3589x; 1.3589x over previous
//
#include <hip/hip_runtime.h>

#define N_   8192
#define FIN  256
#define FOUT 128
#define NW   (N_ / 32)   // bitmask words per row = 256

typedef _Float16 f16x8  __attribute__((ext_vector_type(8)));
typedef _Float16 f16x4  __attribute__((ext_vector_type(4)));
typedef float    f32x16 __attribute__((ext_vector_type(16)));
typedef unsigned int uint;

// ---------------- Kernel 0: pack adj (int32 0/1) -> bitmask (proven streamer) -
__global__ __launch_bounds__(256) void k_pack(
    const int* __restrict__ adj, uint* __restrict__ bm)
{
    const int wid = (blockIdx.x * 256 + threadIdx.x) >> 6;   // row 0..8191
    const int l   = threadIdx.x & 63;
    const int4* __restrict__ arow = (const int4*)(adj + (size_t)wid * N_);
    uint* __restrict__ brow = bm + (size_t)wid * NW;

    #pragma unroll 2
    for (int jb = 0; jb < 32; ++jb) {
        int4 av = arow[jb * 64 + l];
        uint nib = (uint)(av.x != 0) | ((uint)(av.y != 0) << 1)
                 | ((uint)(av.z != 0) << 2) | ((uint)(av.w != 0) << 3);
        uint v = nib | (__shfl_xor(nib, 1, 64) << 4);
        v = v | (__shfl_xor(v, 2, 64) << 8);
        v = v | (__shfl_xor(v, 4, 64) << 16);
        if ((l & 7) == 0)
            brow[jb * 8 + (l >> 3)] = v;
    }
}

// ---------------- Kernel 1: Wh = h @ W, s1 = Wh@a1, s2 = Wh@a2 ----------------
// s1/s2 pre-scaled by 1/ln2 for exp2 in k_attn.
__global__ __launch_bounds__(256) void k_wh(
    const float* __restrict__ h, const float* __restrict__ W,
    const float* __restrict__ a, float* __restrict__ Wh,
    float* __restrict__ s1, float* __restrict__ s2)
{
    __shared__ float hrow[2][FIN];
    __shared__ float rbuf[2][2][2];
    const int t   = threadIdx.x;
    const int rh  = t >> 7;
    const int c   = t & 127;
    const int row = (blockIdx.x << 1) + rh;

    hrow[rh][c]       = h[(size_t)row * FIN + c];
    hrow[rh][c + 128] = h[(size_t)row * FIN + c + 128];
    __syncthreads();

    float acc = 0.f;
    #pragma unroll 8
    for (int k = 0; k < FIN; ++k)
        acc = fmaf(hrow[rh][k], W[k * FOUT + c], acc);

    Wh[(size_t)row * FOUT + c] = acc;

    float p1 = acc * a[c];
    float p2 = acc * a[FOUT + c];
    #pragma unroll
    for (int off = 32; off; off >>= 1) {
        p1 += __shfl_down(p1, off, 64);
        p2 += __shfl_down(p2, off, 64);
    }
    if ((t & 63) == 0) { rbuf[rh][c >> 6][0] = p1; rbuf[rh][c >> 6][1] = p2; }
    __syncthreads();
    if (c == 0) {
        const float k2 = 1.44269504088896f;  // 1/ln2
        s1[row] = (rbuf[rh][0][0] + rbuf[rh][1][0]) * k2;
        s2[row] = (rbuf[rh][0][1] + rbuf[rh][1][1]) * k2;
    }
}

// ------- Kernel 2: transpose+convert Wh -> k-major fp16 WhTt[j/16][128][16] ---
// B-frag loads in k_attn are then 1 KB fully contiguous per instruction.
__global__ __launch_bounds__(256) void k_tr(
    const float* __restrict__ Wh, _Float16* __restrict__ WhTt)
{
    __shared__ float tile[64][129];
    const int t = threadIdx.x;
    const int rbase = blockIdx.x * 64;      // j-range [rbase, rbase+64)

    #pragma unroll
    for (int q = 0; q < 8; ++q) {
        int i4 = q * 256 + t;
        int r  = i4 >> 5;
        int c4 = (i4 & 31) * 4;
        *(float4*)&tile[r][c4] = *(const float4*)&Wh[(size_t)(rbase + r) * FOUT + c4];
    }
    __syncthreads();

    const int c = t >> 1, half = t & 1;     // col 0..127, j-half 0..1
    _Float16 buf[32];
    #pragma unroll
    for (int r = 0; r < 32; ++r) buf[r] = (_Float16)tile[32 * half + r][c];
    // j-tiles of 16: jt0 covers j rbase+32h..+15, jt1 the next 16
    _Float16* d0 = WhTt + ((size_t)(rbase >> 4) + 2 * half) * 2048 + c * 16;
    *(f16x8*)(d0)        = *(f16x8*)&buf[0];
    *(f16x8*)(d0 + 8)    = *(f16x8*)&buf[8];
    *(f16x8*)(d0 + 2048)     = *(f16x8*)&buf[16];
    *(f16x8*)(d0 + 2048 + 8) = *(f16x8*)&buf[24];
}

// ---------------- Kernel 3: 32x32x16 MFMA, barrier-free, low-L1-traffic -------
// Grid: 512 = 64 row-superblocks(128 rows) x 8 j-splits; block = 4 waves, each
// wave owns 32 rows x 1024 j (64 tiles of 16 j). One A-frag covers 32 rows ->
// B bytes per wave halved vs 16x16 (512 MB total through L1). No LDS/barriers.
__global__ __launch_bounds__(256, 2) void k_attn(
    const uint* __restrict__ bm, const _Float16* __restrict__ WhTt,
    const float* __restrict__ s1g, const float* __restrict__ s2g,
    _Float16* __restrict__ num_g, float* __restrict__ den_g)
{
    const int t = threadIdx.x;
    const int w = t >> 6, l = t & 63;
    const int n31 = l & 31, h = l >> 5;
    const int shiftH = h << 3;

    const int sp    = blockIdx.x & 7;
    const int rbase = (blockIdx.x >> 3) * 128 + w * 32;
    const int jbase = sp * 1024;

    const int   row = rbase + n31;
    const float s1r = s1g[row];
    const uint*     __restrict__ mrow = bm + (size_t)row * NW + sp * 32;
    const float*    __restrict__ s2p  = s2g + jbase + 8 * h;
    const _Float16* __restrict__ bpt  =
        WhTt + (size_t)(sp * 64) * 2048 + n31 * 16 + 8 * h;

    f32x16 acc0 = {0.f}, acc1 = {0.f}, acc2 = {0.f}, acc3 = {0.f};
    #pragma unroll
    for (int q = 0; q < 16; ++q) { acc0[q]=0.f; acc1[q]=0.f; acc2[q]=0.f; acc3[q]=0.f; }
    float denp = 0.f;

    auto computeP = [&](uint byte, const float4& s0, const float4& s1v) -> f16x8 {
        const float bias = -5.77078016f;   // -4/ln2
        float m, e;
        f16x8 pv;
        m = s1r + s0.x;  e = fmaxf(m, 0.2f * m); pv[0] = (_Float16)((byte & 1u)   ? __builtin_amdgcn_exp2f(e + bias) : 0.f);
        m = s1r + s0.y;  e = fmaxf(m, 0.2f * m); pv[1] = (_Float16)((byte & 2u)   ? __builtin_amdgcn_exp2f(e + bias) : 0.f);
        m = s1r + s0.z;  e = fmaxf(m, 0.2f * m); pv[2] = (_Float16)((byte & 4u)   ? __builtin_amdgcn_exp2f(e + bias) : 0.f);
        m = s1r + s0.w;  e = fmaxf(m, 0.2f * m); pv[3] = (_Float16)((byte & 8u)   ? __builtin_amdgcn_exp2f(e + bias) : 0.f);
        m = s1r + s1v.x; e = fmaxf(m, 0.2f * m); pv[4] = (_Float16)((byte & 16u)  ? __builtin_amdgcn_exp2f(e + bias) : 0.f);
        m = s1r + s1v.y; e = fmaxf(m, 0.2f * m); pv[5] = (_Float16)((byte & 32u)  ? __builtin_amdgcn_exp2f(e + bias) : 0.f);
        m = s1r + s1v.z; e = fmaxf(m, 0.2f * m); pv[6] = (_Float16)((byte & 64u)  ? __builtin_amdgcn_exp2f(e + bias) : 0.f);
        m = s1r + s1v.w; e = fmaxf(m, 0.2f * m); pv[7] = (_Float16)((byte & 128u) ? __builtin_amdgcn_exp2f(e + bias) : 0.f);
        denp += (float)pv[0] + (float)pv[1] + (float)pv[2] + (float)pv[3]
              + (float)pv[4] + (float)pv[5] + (float)pv[6] + (float)pv[7];
        return pv;
    };

    // one tile: prefetch B(t+1) into n*, P(t) from regs, reload s2 slot w/ t+2,
    // 4 MFMAs with c*. Caller alternates c*/n* roles.
    auto tileStep = [&](int tt, int hi16, uint mk,
                        f16x8& c0, f16x8& c1, f16x8& c2, f16x8& c3,
                        f16x8& d0, f16x8& d1, f16x8& d2, f16x8& d3,
                        float4& sv0, float4& sv1) {
        const int tn = (tt + 1 < 64) ? tt + 1 : 63;
        const _Float16* p = bpt + (size_t)tn * 2048;
        d0 = *(const f16x8*)(p);
        d1 = *(const f16x8*)(p + 512);
        d2 = *(const f16x8*)(p + 1024);
        d3 = *(const f16x8*)(p + 1536);

        f16x8 pv = computeP((mk >> (hi16 + shiftH)) & 255u, sv0, sv1);

        const int ts = (tt + 2 < 64) ? tt + 2 : 63;
        sv0 = *(const float4*)(s2p + ts * 16);
        sv1 = *(const float4*)(s2p + ts * 16 + 4);

        __builtin_amdgcn_s_setprio(1);
        acc0 = __builtin_amdgcn_mfma_f32_32x32x16_f16(pv, c0, acc0, 0, 0, 0);
        acc1 = __builtin_amdgcn_mfma_f32_32x32x16_f16(pv, c1, acc1, 0, 0, 0);
        acc2 = __builtin_amdgcn_mfma_f32_32x32x16_f16(pv, c2, acc2, 0, 0, 0);
        acc3 = __builtin_amdgcn_mfma_f32_32x32x16_f16(pv, c3, acc3, 0, 0, 0);
        __builtin_amdgcn_s_setprio(0);
    };

    // prologue
    uint mk0 = mrow[0], mk1 = mrow[1];
    float4 sA0 = *(const float4*)(s2p);
    float4 sA1 = *(const float4*)(s2p + 4);
    float4 sB0 = *(const float4*)(s2p + 16);
    float4 sB1 = *(const float4*)(s2p + 20);
    f16x8 c0, c1, c2, c3, n0, n1, n2, n3;
    c0 = *(const f16x8*)(bpt);
    c1 = *(const f16x8*)(bpt + 512);
    c2 = *(const f16x8*)(bpt + 1024);
    c3 = *(const f16x8*)(bpt + 1536);

    for (int tt = 0; tt < 64; tt += 4) {
        const int wi = tt >> 1;
        tileStep(tt,     0,  mk0, c0,c1,c2,c3, n0,n1,n2,n3, sA0, sA1);
        tileStep(tt + 1, 16, mk0, n0,n1,n2,n3, c0,c1,c2,c3, sB0, sB1);
        mk0 = mrow[(wi + 2 < 32) ? wi + 2 : 31];
        tileStep(tt + 2, 0,  mk1, c0,c1,c2,c3, n0,n1,n2,n3, sA0, sA1);
        tileStep(tt + 3, 16, mk1, n0,n1,n2,n3, c0,c1,c2,c3, sB0, sB1);
        mk1 = mrow[(wi + 3 < 32) ? wi + 3 : 31];
    }

    // den: lanes l and l^32 hold the two k-halves of the same row
    denp += __shfl_xor(denp, 32, 64);
    if (l < 32)
        den_g[(size_t)sp * N_ + row] = denp;

    // num partials (f16): C/D layout col=l&31, row=(q&3)+8*(q>>2)+4*h
    #pragma unroll
    for (int q = 0; q < 16; ++q) {
        const int rl = (q & 3) + 8 * (q >> 2) + 4 * h;
        _Float16* o = num_g + ((size_t)sp * N_ + rbase + rl) * FOUT + n31;
        o[0]  = (_Float16)acc0[q];
        o[32] = (_Float16)acc1[q];
        o[64] = (_Float16)acc2[q];
        o[96] = (_Float16)acc3[q];
    }
}

// ---------------- Kernel 4: combine 8 j-splits and normalize ------------------
__global__ __launch_bounds__(256) void k_norm(
    const _Float16* __restrict__ num_g, const float* __restrict__ den_g,
    float* __restrict__ out)
{
    const int idx4 = blockIdx.x * 256 + threadIdx.x;
    const int i  = idx4 >> 5;
    const int c4 = (idx4 & 31) * 4;

    float4 s = {0.f, 0.f, 0.f, 0.f};
    float  d = 0.f;
    #pragma unroll
    for (int sp = 0; sp < 8; ++sp) {
        f16x4 v = *(const f16x4*)(num_g + ((size_t)sp * N_ + i) * FOUT + c4);
        s.x += (float)v[0]; s.y += (float)v[1];
        s.z += (float)v[2]; s.w += (float)v[3];
        d += den_g[(size_t)sp * N_ + i];
    }
    const float inv = 1.f / d;
    float4 o = {s.x * inv, s.y * inv, s.z * inv, s.w * inv};
    *(float4*)&out[(size_t)i * FOUT + c4] = o;
}

extern "C" void kernel_launch(void* const* d_in, const int* in_sizes, int n_in,
                              void* d_out, int out_size, void* d_ws, size_t ws_size,
                              hipStream_t stream) {
    const float* h   = (const float*)d_in[0];
    const int*   adj = (const int*)d_in[1];
    const float* W   = (const float*)d_in[2];
    const float* a   = (const float*)d_in[3];
    float* out = (float*)d_out;

    char* ws = (char*)d_ws;
    float*    Wh   = (float*)ws;                           // 0..4 MB
    _Float16* WhTt = (_Float16*)(ws + (4u << 20));         // 4..6 MB
    float*    s1   = (float*)(ws + (6u << 20));            // 32 KB
    float*    s2   = (float*)(ws + (6u << 20) + 32768);    // 32 KB
    _Float16* num  = (_Float16*)(ws + (7u << 20));         // 7..23 MB (f16)
    float*    den  = (float*)(ws + (23u << 20));           // 256 KB
    uint*     bmk  = (uint*)(ws + (24u << 20));            // 24..32 MB

    k_pack<<<2048,   256, 0, stream>>>(adj, bmk);
    k_wh  <<<N_ / 2, 256, 0, stream>>>(h, W, a, Wh, s1, s2);
    k_tr  <<<N_ / 64, 256, 0, stream>>>(Wh, WhTt);
    k_attn<<<512,   256, 0, stream>>>(bmk, WhTt, s1, s2, num, den);
    k_norm<<<1024,  256, 0, stream>>>(num, den, out);
}